// Round 9
// baseline (170.864 us; speedup 1.0000x reference)
//
#include <hip/hip_runtime.h>

#define NROWS 8192
#define BQ    4096
#define DDIM  256
#define NSLC  256                    // 128 row-side + 128 col-side slices
#define INV_T (1.0f/0.07f)
#define K2EXP (1.4426950408889634f/0.07f)   // log2(e)/T

typedef short bf16x8 __attribute__((ext_vector_type(8)));
typedef float f32x4  __attribute__((ext_vector_type(4)));
typedef unsigned short u16;

__device__ __forceinline__ u16 f2bf(float f) {
  unsigned u = __float_as_uint(f);
  u += 0x7fffu + ((u >> 16) & 1u);   // round-to-nearest-even
  return (u16)(u >> 16);
}

// ---------------- kernel 1: L2-normalize rows of [z_i; z_j], cast to bf16 ----
// Also zeroes the scalar output and the 16 MB slice-partial buffer
// (8 coalesced stores/thread; stream-ordered, simloss/loss run after).
__global__ void norm_cast_kernel(const float* __restrict__ zi,
                                 const float* __restrict__ zj,
                                 u16* __restrict__ zb,
                                 float* __restrict__ partials,  // 2*NSLC*NROWS
                                 float* __restrict__ out) {
  if (blockIdx.x == 0 && threadIdx.x == 0) *out = 0.0f;
  {
    unsigned gid = blockIdx.x * 256 + threadIdx.x;   // 524288 threads
    #pragma unroll
    for (int i = 0; i < 8; ++i)                      // 8*524288 == 2*NSLC*NROWS
      partials[(size_t)i * 524288 + gid] = 0.0f;
  }
  int wave = threadIdx.x >> 6;
  int lane = threadIdx.x & 63;
  int row  = blockIdx.x * 4 + wave;            // one wave per row, 4 rows/block
  const float* src = (row < BQ) ? (zi + (size_t)row * DDIM)
                                : (zj + (size_t)(row - BQ) * DDIM);
  float4 v = ((const float4*)src)[lane];       // 64 lanes x float4 = 256
  float s = v.x*v.x + v.y*v.y + v.z*v.z + v.w*v.w;
  #pragma unroll
  for (int m = 32; m; m >>= 1) s += __shfl_xor(s, m, 64);
  float scale = 1.0f / fmaxf(sqrtf(s), 1e-12f);
  ushort4 o;
  o.x = f2bf(v.x * scale); o.y = f2bf(v.y * scale);
  o.z = f2bf(v.z * scale); o.w = f2bf(v.w * scale);
  ((ushort4*)(zb + (size_t)row * DDIM))[lane] = o;
}

// ---------------- kernel 2: fused sim GEMM + mask + pos/negexp partials ------
#define GL2LDS(gp, lp) \
  __builtin_amdgcn_global_load_lds((__attribute__((address_space(1))) void*)(gp), \
                                   (__attribute__((address_space(3))) void*)(lp), 16, 0, 0)

// LEDGER (do not re-try):
//  * r2 min-waves-4 launch bound: 128-reg cap spilled acc -> 620 MB scratch.
//  * r1/r3 deep REGISTER pipeline for B: ~210 live regs -> 34 MB scratch.
//  * r3 persistent 64KB A-tile: 2 blk/CU, occ 11%, 103us.
//  * r4 manual vmcnt/s_barrier dbuf: VGPR 180, occ 10.8%, 96us.
//  * r5 grid 512->1024 col-splits: occupancy unchanged; dur unchanged.
//  * r6 symmetry + atomicAdd: atomics = 20.7MB write-through + serialization.
//  * r8 symmetry + slice stores, 64x16 grid with holes + persistent dual
//    epilogue: VGPR 188 (2 waves/SIMD) + 544/1024 working blocks with 1-4
//    tile spread -> occ 7.3%, 79.7us. MFMA-busy 6.5us confirms half-work OK.
// This version keeps the symmetry math VERBATIM and fixes the two r8 killers:
//  * BALANCED flat grid: 520 blocks x exactly 4 tiles (2080 = 520*4), tile
//    u = b*4+t decoded (rb,c) by the r6-proven triangular sqrt+fixup.
//  * REGISTER DIET: no rowidx (diag test = index algebra on diag tiles);
//    row/col partials are per-tile-local, stored per tile; uniform epilogue.
//    K-loop live set: rowlab[16]+clab[4]+staging addrs (< r0's).
//  * row-side partial of tile (rb,c): slice 2c+wc;  col-side (mirror,
//    c>rb only): slice 128+2rb+wr. Unique writer per (slice,row) cell;
//    unwritten cells read the norm_cast zero-fill. No atomics.
__global__ __launch_bounds__(256) void simloss_kernel(
    const u16* __restrict__ zb, const int* __restrict__ labels,
    float* __restrict__ pos_p, float* __restrict__ neg_p) {
  // row-major [128][32] bf16, chunk-SWIZZLED: row r's 8-elt chunk cc lives at
  // slot cc ^ ((r>>1)&3); spreads each quad's 16 lanes over all 16 bank-groups
  // -> 2-way = free. (measured: SQ_LDS_BANK_CONFLICT = 0)
  __shared__ __align__(16) u16 lsA[128 * 32];
  __shared__ __align__(16) u16 lsB[128 * 32];

  const int tid  = threadIdx.x;
  const int w    = tid >> 6;         // wave 0..3
  const int lane = tid & 63;
  const int ln   = lane & 15;        // MFMA n/m lane index
  const int qd   = lane >> 4;        // MFMA quad
  const int wr   = w >> 1;           // wave row (0..1) in 2x2 wave grid
  const int wc   = w & 1;            // wave col

  const int strow = lane >> 2;       // staging: 16 rows per load instr
  const int slot  = lane & 3;        // LDS chunk position this lane fills
  const int stk   = (slot ^ ((strow >> 1) & 3)) * 8;  // global chunk to fetch
  const int rdsw  = (ln >> 1) & 3;   // read-side swizzle key

  #pragma unroll 1
  for (int t = 0; t < 4; ++t) {
    const int u = blockIdx.x * 4 + t;            // tile id 0..2079
    // triangular decode: T(r) = r*(129-r)/2 tiles precede row panel r
    int rb = (int)((129.0f - sqrtf((float)(16641 - 8 * u))) * 0.5f);
    while ((rb + 1) * (129 - (rb + 1)) / 2 <= u) ++rb;   // float-boundary fixup
    while (rb * (129 - rb) / 2 > u) --rb;
    const int c  = rb + (u - rb * (129 - rb) / 2);       // col panel, c >= rb
    const int r0 = rb * 128;
    const int c0 = c * 128;
    const bool isdiag = (rb == c);

    int rowlab[16], clab[4];
    #pragma unroll
    for (int ri = 0; ri < 4; ++ri)
      #pragma unroll
      for (int r = 0; r < 4; ++r) {
        int row = r0 + wr * 64 + ri * 16 + qd * 4 + r;   // C/D: row = quad*4+reg
        rowlab[ri * 4 + r] = labels[row & (BQ - 1)];     // labels[row % B]
      }
    #pragma unroll
    for (int mi = 0; mi < 4; ++mi)
      clab[mi] = labels[(c0 + wc * 64 + mi * 16 + ln) & (BQ - 1)];

    const f32x4 z4 = {0.f, 0.f, 0.f, 0.f};
    f32x4 acc[4][4];
    #pragma unroll
    for (int ri = 0; ri < 4; ++ri)
      #pragma unroll
      for (int mi = 0; mi < 4; ++mi) acc[ri][mi] = z4;

    for (int kk = 0; kk < 8; ++kk) {             // K = 256, BK = 32 (r0 verbatim)
      const int k0 = kk * 32;
      #pragma unroll
      for (int j = 0; j < 2; ++j) {              // wave stages 32 rows of A and B
        int rbase = w * 32 + j * 16;
        const u16* ga = zb + (size_t)(r0 + rbase + strow) * DDIM + k0 + stk;
        GL2LDS(ga, &lsA[rbase * 32]);
        const u16* gb = zb + (size_t)(c0 + rbase + strow) * DDIM + k0 + stk;
        GL2LDS(gb, &lsB[rbase * 32]);
      }
      __syncthreads();                           // drains vmcnt before barrier

      bf16x8 av[4], bv[4];
      #pragma unroll
      for (int ri = 0; ri < 4; ++ri)             // A[m=ln][k=qd*8+j], swizzled slot
        av[ri] = *(const bf16x8*)&lsA[(wr * 64 + ri * 16 + ln) * 32 + (qd ^ rdsw) * 8];
      #pragma unroll
      for (int mi = 0; mi < 4; ++mi)             // B[n=ln][k=qd*8+j] (B^T input)
        bv[mi] = *(const bf16x8*)&lsB[(wc * 64 + mi * 16 + ln) * 32 + (qd ^ rdsw) * 8];
      #pragma unroll
      for (int ri = 0; ri < 4; ++ri)
        #pragma unroll
        for (int mi = 0; mi < 4; ++mi)
          acc[ri][mi] = __builtin_amdgcn_mfma_f32_16x16x32_bf16(
              av[ri], bv[mi], acc[ri][mi], 0, 0, 0);
      __syncthreads();
    }

    // ---- per-tile epilogue (all partials tile-local; stored immediately) ---
    float rp[16], rn[16], cp[4], cn[4];
    #pragma unroll
    for (int i = 0; i < 16; ++i) { rp[i] = 0.0f; rn[i] = 0.0f; }
    #pragma unroll
    for (int mi = 0; mi < 4; ++mi) { cp[mi] = 0.0f; cn[mi] = 0.0f; }

    #pragma unroll
    for (int ri = 0; ri < 4; ++ri)
      #pragma unroll
      for (int mi = 0; mi < 4; ++mi) {
        f32x4 v = acc[ri][mi];
        #pragma unroll
        for (int r = 0; r < 4; ++r) {
          int slt = ri * 4 + r;
          float s = v[r];
          bool same = (rowlab[slt] == clab[mi]);
          // diag element only exists on diagonal tiles; pure index algebra
          bool diag = isdiag && (wr == wc) && (ri == mi) && (ln == qd * 4 + r);
          float e = same ? 0.0f : __builtin_amdgcn_exp2f(s * K2EXP);
          float p = (same && !diag) ? s : 0.0f;
          rp[slt] += p;  rn[slt] += e;
          cp[mi]  += p;  cn[mi]  += e;
        }
      }

    // row-side reduce over the 16 lanes (ln axis) and store, slice 2c+wc
    #pragma unroll
    for (int i = 0; i < 16; ++i) {
      #pragma unroll
      for (int m = 1; m < 16; m <<= 1) {
        rp[i] += __shfl_xor(rp[i], m, 64);
        rn[i] += __shfl_xor(rn[i], m, 64);
      }
    }
    if (ln == 0) {
      const size_t srs = (size_t)(2 * c + wc) * NROWS;
      #pragma unroll
      for (int i = 0; i < 16; ++i) {
        int row = r0 + wr * 64 + (i >> 2) * 16 + qd * 4 + (i & 3);
        pos_p[srs + row] = rp[i];
        neg_p[srs + row] = rn[i];
      }
    }

    // col-side (mirror) reduce over rows (qd axis) and store, slice 128+2rb+wr
    if (!isdiag) {
      #pragma unroll
      for (int mi = 0; mi < 4; ++mi) {
        cp[mi] += __shfl_xor(cp[mi], 16, 64);
        cp[mi] += __shfl_xor(cp[mi], 32, 64);
        cn[mi] += __shfl_xor(cn[mi], 16, 64);
        cn[mi] += __shfl_xor(cn[mi], 32, 64);
      }
      if (qd == 0) {
        const size_t scs = (size_t)(128 + 2 * rb + wr) * NROWS;
        #pragma unroll
        for (int mi = 0; mi < 4; ++mi) {
          int col = c0 + wc * 64 + mi * 16 + ln;
          pos_p[scs + col] = cp[mi];
          neg_p[scs + col] = cn[mi];
        }
      }
    }
  }
}

// ---------------- kernel 3: per-row loss + mean (parallel, atomic) -----------
__global__ void loss_kernel(const float* __restrict__ pos_p,
                            const float* __restrict__ neg_p,
                            float* __restrict__ out) {
  int row = blockIdx.x * 64 + threadIdx.x;       // 128 blocks x 64 threads
  float p = 0.0f, n = 0.0f;
  #pragma unroll 8
  for (int s = 0; s < NSLC; ++s) {
    p += pos_p[(size_t)s * NROWS + row];
    n += neg_p[(size_t)s * NROWS + row];
  }
  float l = log1pf(expf(logf(n) - p * INV_T));
  #pragma unroll
  for (int m = 32; m; m >>= 1) l += __shfl_xor(l, m, 64);
  if (threadIdx.x == 0) atomicAdd(out, l * (1.0f / NROWS));
}

// ---------------- launcher ---------------------------------------------------
extern "C" void kernel_launch(void* const* d_in, const int* in_sizes, int n_in,
                              void* d_out, int out_size, void* d_ws, size_t ws_size,
                              hipStream_t stream) {
  const float* zi     = (const float*)d_in[0];
  const float* zj     = (const float*)d_in[1];
  const int*   labels = (const int*)d_in[2];
  float*       out    = (float*)d_out;

  char* w = (char*)d_ws;
  u16*   zb    = (u16*)w;                                          // 4 MB bf16 Z
  float* pos_p = (float*)(w + (size_t)NROWS * DDIM * sizeof(u16)); // 256x8192 f32
  float* neg_p = pos_p + (size_t)NSLC * NROWS;                     // 256x8192 f32

  hipLaunchKernelGGL(norm_cast_kernel, dim3(2048), dim3(256), 0, stream,
                     zi, zj, zb, pos_p, out);
  hipLaunchKernelGGL(simloss_kernel, dim3(520), dim3(256), 0, stream,
                     zb, labels, pos_p, neg_p);
  hipLaunchKernelGGL(loss_kernel, dim3(128), dim3(64), 0, stream,
                     pos_p, neg_p, out);
}

// Round 10
// 127.311 us; speedup vs baseline: 1.3421x; 1.3421x over previous
//
#include <hip/hip_runtime.h>

#define NROWS 8192
#define BQ    4096
#define DDIM  256
#define NSLC  192                    // 64 row-side + 128 col-side slices
#define INV_T (1.0f/0.07f)
#define K2EXP (1.4426950408889634f/0.07f)   // log2(e)/T

typedef short bf16x8 __attribute__((ext_vector_type(8)));
typedef float f32x4  __attribute__((ext_vector_type(4)));
typedef unsigned short u16;

__device__ __forceinline__ u16 f2bf(float f) {
  unsigned u = __float_as_uint(f);
  u += 0x7fffu + ((u >> 16) & 1u);   // round-to-nearest-even
  return (u16)(u >> 16);
}

// ---------------- kernel 1: L2-normalize rows of [z_i; z_j], cast to bf16 ----
// Also zeroes the scalar output and the 12.6 MB slice-partial buffer
// (6 coalesced stores/thread; stream-ordered, simloss/loss run after).
__global__ void norm_cast_kernel(const float* __restrict__ zi,
                                 const float* __restrict__ zj,
                                 u16* __restrict__ zb,
                                 float* __restrict__ partials,  // 2*NSLC*NROWS
                                 float* __restrict__ out) {
  if (blockIdx.x == 0 && threadIdx.x == 0) *out = 0.0f;
  {
    unsigned gid = blockIdx.x * 256 + threadIdx.x;   // 524288 threads
    #pragma unroll
    for (int i = 0; i < 6; ++i)                      // 6*524288 == 2*NSLC*NROWS
      partials[(size_t)i * 524288 + gid] = 0.0f;
  }
  int wave = threadIdx.x >> 6;
  int lane = threadIdx.x & 63;
  int row  = blockIdx.x * 4 + wave;            // one wave per row, 4 rows/block
  const float* src = (row < BQ) ? (zi + (size_t)row * DDIM)
                                : (zj + (size_t)(row - BQ) * DDIM);
  float4 v = ((const float4*)src)[lane];       // 64 lanes x float4 = 256
  float s = v.x*v.x + v.y*v.y + v.z*v.z + v.w*v.w;
  #pragma unroll
  for (int m = 32; m; m >>= 1) s += __shfl_xor(s, m, 64);
  float scale = 1.0f / fmaxf(sqrtf(s), 1e-12f);
  ushort4 o;
  o.x = f2bf(v.x * scale); o.y = f2bf(v.y * scale);
  o.z = f2bf(v.z * scale); o.w = f2bf(v.w * scale);
  ((ushort4*)(zb + (size_t)row * DDIM))[lane] = o;
}

// ---------------- kernel 2: fused sim GEMM + mask + pos/negexp partials ------
#define GL2LDS(gp, lp) \
  __builtin_amdgcn_global_load_lds((__attribute__((address_space(1))) void*)(gp), \
                                   (__attribute__((address_space(3))) void*)(lp), 16, 0, 0)

// LEDGER (do not re-try):
//  * r2 min-waves-4 bound: reg cap spilled acc (620 MB scratch).
//  * r1/r3 deep register pipeline: spill. r3 persistent 64KB A: occ 11%.
//  * r4 manual vmcnt/s_barrier dbuf: VGPR 180, occ 10.8%, 96us.
//  * r6 atomics: 20.7MB write-through. r8 holey grid: occ 7.3%.
//  * r9 520x4 balanced: remainder-8 tail => wall = 3 rounds not 2 (+50%),
//    and per-tile label gathers + stores kept pv at 6.8us vs r0's 3.73.
// MODEL (10 data points): wall = (max blocks/CU) x T_block; pv = 3.7us when
// labels/prologue amortize over many tiles, ~6.8us when paid per tile.
// This version: symmetry (verified 3x) + r0 inner K-loop VERBATIM +
//  * grid EXACTLY 512 (2 blocks/CU, zero tail): 480x4 + 32x5 = 2080 tiles.
//  * pair-balanced decode, NO sqrt: pair p = u/65 covers row p (cols p..63)
//    then row 63-p (cols 63-p..63); consecutive u share rb.
//  * rowlab + row-side flush only on ROW CHANGE (1-3x per block, r0-style).
//  * col labels: one 512B global_load_lds per tile (4 cache lines, not 64),
//    read from LDS after the kk=0 barrier (reads done long before the next
//    tile's staging, which follows the kk=7 barrier -> race-free).
//  * slices: row-side (b&31)*2+wc (<=18 consecutive blocks touch a row ->
//    b&31 unique); col-side 64+2rb+wr. Zero-filled; unique writer per cell.
__global__ __launch_bounds__(256) void simloss_kernel(
    const u16* __restrict__ zb, const int* __restrict__ labels,
    float* __restrict__ pos_p, float* __restrict__ neg_p) {
  // row-major [128][32] bf16, chunk-SWIZZLED: row r's 8-elt chunk cc lives at
  // slot cc ^ ((r>>1)&3) -> 2-way = free. (measured: SQ_LDS_BANK_CONFLICT = 0)
  __shared__ __align__(16) u16 lsA[128 * 32];
  __shared__ __align__(16) u16 lsB[128 * 32];
  __shared__ __align__(16) int lsLab[128];

  const int tid  = threadIdx.x;
  const int w    = tid >> 6;         // wave 0..3
  const int lane = tid & 63;
  const int ln   = lane & 15;        // MFMA n/m lane index
  const int qd   = lane >> 4;        // MFMA quad
  const int wr   = w >> 1;           // wave row (0..1) in 2x2 wave grid
  const int wc   = w & 1;            // wave col

  const int strow = lane >> 2;       // staging: 16 rows per load instr
  const int slot  = lane & 3;        // LDS chunk position this lane fills
  const int stk   = (slot ^ ((strow >> 1) & 3)) * 8;  // global chunk to fetch
  const int rdsw  = (ln >> 1) & 3;   // read-side swizzle key

  const int b = blockIdx.x;
  int base, nt;
  if (b < 480) { base = b * 4;                nt = 4; }
  else         { base = 1920 + (b - 480) * 5; nt = 5; }
  const size_t srow = (size_t)((b & 31) * 2 + wc) * NROWS;  // row-side slice

  float rp[16], rn[16];
  int rowlab[16];
  int cur_rb = -1;

  #pragma unroll 1
  for (int t = 0; t < nt; ++t) {
    const int u = base + t;
    const int p = u / 65;              // pair 0..31 (magic-mul)
    const int v = u - p * 65;
    int rb, c;
    if (v < 64 - p) { rb = p;      c = p + v; }   // row A of pair
    else            { rb = 63 - p; c = v - 1; }   // row B of pair
    const int r0 = rb * 128, c0 = c * 128;
    const bool isdiag = (rb == c);

    if (rb != cur_rb) {                // uniform branch (u uniform per block)
      if (cur_rb >= 0) {               // flush row-side partials of old row
        #pragma unroll
        for (int i = 0; i < 16; ++i) {
          #pragma unroll
          for (int m = 1; m < 16; m <<= 1) {
            rp[i] += __shfl_xor(rp[i], m, 64);
            rn[i] += __shfl_xor(rn[i], m, 64);
          }
        }
        if (ln == 0) {
          #pragma unroll
          for (int i = 0; i < 16; ++i) {
            int row = cur_rb * 128 + wr * 64 + (i >> 2) * 16 + qd * 4 + (i & 3);
            pos_p[srow + row] = rp[i];
            neg_p[srow + row] = rn[i];
          }
        }
      }
      cur_rb = rb;
      #pragma unroll
      for (int ri = 0; ri < 4; ++ri)
        #pragma unroll
        for (int r = 0; r < 4; ++r)
          rowlab[ri * 4 + r] = labels[(r0 + wr * 64 + ri * 16 + qd * 4 + r) & (BQ - 1)];
      #pragma unroll
      for (int i = 0; i < 16; ++i) { rp[i] = 0.0f; rn[i] = 0.0f; }
    }

    const f32x4 z4 = {0.f, 0.f, 0.f, 0.f};
    f32x4 acc[4][4];
    #pragma unroll
    for (int ri = 0; ri < 4; ++ri)
      #pragma unroll
      for (int mi = 0; mi < 4; ++mi) acc[ri][mi] = z4;

    int clab[4];
    #pragma unroll
    for (int kk = 0; kk < 8; ++kk) {             // K = 256, BK = 32 (r0 verbatim)
      const int k0 = kk * 32;
      #pragma unroll
      for (int j = 0; j < 2; ++j) {              // wave stages 32 rows of A and B
        int rbase = w * 32 + j * 16;
        const u16* ga = zb + (size_t)(r0 + rbase + strow) * DDIM + k0 + stk;
        GL2LDS(ga, &lsA[rbase * 32]);
        const u16* gb = zb + (size_t)(c0 + rbase + strow) * DDIM + k0 + stk;
        GL2LDS(gb, &lsB[rbase * 32]);
      }
      if (kk == 0 && tid < 32)                   // this tile's 128 col labels
        GL2LDS(labels + (c0 & (BQ - 1)) + tid * 4, &lsLab[0]);
      __syncthreads();                           // drains vmcnt before barrier
      if (kk == 0) {
        #pragma unroll
        for (int mi = 0; mi < 4; ++mi) clab[mi] = lsLab[wc * 64 + mi * 16 + ln];
      }

      bf16x8 av[4], bv[4];
      #pragma unroll
      for (int ri = 0; ri < 4; ++ri)             // A[m=ln][k=qd*8+j], swizzled slot
        av[ri] = *(const bf16x8*)&lsA[(wr * 64 + ri * 16 + ln) * 32 + (qd ^ rdsw) * 8];
      #pragma unroll
      for (int mi = 0; mi < 4; ++mi)             // B[n=ln][k=qd*8+j] (B^T input)
        bv[mi] = *(const bf16x8*)&lsB[(wc * 64 + mi * 16 + ln) * 32 + (qd ^ rdsw) * 8];
      #pragma unroll
      for (int ri = 0; ri < 4; ++ri)
        #pragma unroll
        for (int mi = 0; mi < 4; ++mi)
          acc[ri][mi] = __builtin_amdgcn_mfma_f32_16x16x32_bf16(
              av[ri], bv[mi], acc[ri][mi], 0, 0, 0);
      __syncthreads();
    }

    // ---- per-tile epilogue: row-side accumulates, col-side stores ----------
    float cp[4] = {0.f, 0.f, 0.f, 0.f}, cn[4] = {0.f, 0.f, 0.f, 0.f};
    #pragma unroll
    for (int ri = 0; ri < 4; ++ri)
      #pragma unroll
      for (int mi = 0; mi < 4; ++mi) {
        f32x4 vv = acc[ri][mi];
        #pragma unroll
        for (int r = 0; r < 4; ++r) {
          int slt = ri * 4 + r;
          float s = vv[r];
          bool same = (rowlab[slt] == clab[mi]);
          bool diag = isdiag && (wr == wc) && (ri == mi) && (ln == qd * 4 + r);
          float e = same ? 0.0f : __builtin_amdgcn_exp2f(s * K2EXP);
          float pp = (same && !diag) ? s : 0.0f;
          rp[slt] += pp;  rn[slt] += e;
          cp[mi]  += pp;  cn[mi]  += e;
        }
      }

    if (!isdiag) {   // mirror: column sums feed panel c (bitwise-equal tile)
      #pragma unroll
      for (int mi = 0; mi < 4; ++mi) {
        cp[mi] += __shfl_xor(cp[mi], 16, 64);
        cp[mi] += __shfl_xor(cp[mi], 32, 64);
        cn[mi] += __shfl_xor(cn[mi], 16, 64);
        cn[mi] += __shfl_xor(cn[mi], 32, 64);
      }
      if (qd == 0) {
        const size_t scs = (size_t)(64 + 2 * rb + wr) * NROWS;
        #pragma unroll
        for (int mi = 0; mi < 4; ++mi) {
          int col = c0 + wc * 64 + mi * 16 + ln;   // 16 consecutive dwords
          pos_p[scs + col] = cp[mi];
          neg_p[scs + col] = cn[mi];
        }
      }
    }
  }

  // final row-side flush (cur_rb always valid here)
  #pragma unroll
  for (int i = 0; i < 16; ++i) {
    #pragma unroll
    for (int m = 1; m < 16; m <<= 1) {
      rp[i] += __shfl_xor(rp[i], m, 64);
      rn[i] += __shfl_xor(rn[i], m, 64);
    }
  }
  if (ln == 0) {
    #pragma unroll
    for (int i = 0; i < 16; ++i) {
      int row = cur_rb * 128 + wr * 64 + (i >> 2) * 16 + qd * 4 + (i & 3);
      pos_p[srow + row] = rp[i];
      neg_p[srow + row] = rn[i];
    }
  }
}

// ---------------- kernel 3: per-row loss + mean (parallel) -------------------
// 128 blocks x 256 threads; wave sg sums slices [sg*48, sg*48+48) for 64
// consecutive rows (each load = 64 consecutive dwords, fully coalesced),
// then LDS-reduce across the 4 waves.
__global__ void loss_kernel(const float* __restrict__ pos_p,
                            const float* __restrict__ neg_p,
                            float* __restrict__ out) {
  const int r   = threadIdx.x & 63;
  const int sg  = threadIdx.x >> 6;              // slice group 0..3
  const int row = blockIdx.x * 64 + r;
  float p = 0.0f, n = 0.0f;
  #pragma unroll 4
  for (int s = sg * 48; s < sg * 48 + 48; ++s) {
    p += pos_p[(size_t)s * NROWS + row];
    n += neg_p[(size_t)s * NROWS + row];
  }
  __shared__ float redp[4][64], redn[4][64];
  redp[sg][r] = p; redn[sg][r] = n;
  __syncthreads();
  if (sg == 0) {
    p = redp[0][r] + redp[1][r] + redp[2][r] + redp[3][r];
    n = redn[0][r] + redn[1][r] + redn[2][r] + redn[3][r];
    float l = log1pf(expf(logf(n) - p * INV_T));
    #pragma unroll
    for (int m = 32; m; m >>= 1) l += __shfl_xor(l, m, 64);
    if (r == 0) atomicAdd(out, l * (1.0f / NROWS));
  }
}

// ---------------- launcher ---------------------------------------------------
extern "C" void kernel_launch(void* const* d_in, const int* in_sizes, int n_in,
                              void* d_out, int out_size, void* d_ws, size_t ws_size,
                              hipStream_t stream) {
  const float* zi     = (const float*)d_in[0];
  const float* zj     = (const float*)d_in[1];
  const int*   labels = (const int*)d_in[2];
  float*       out    = (float*)d_out;

  char* w = (char*)d_ws;
  u16*   zb    = (u16*)w;                                          // 4 MB bf16 Z
  float* pos_p = (float*)(w + (size_t)NROWS * DDIM * sizeof(u16)); // 192x8192 f32
  float* neg_p = pos_p + (size_t)NSLC * NROWS;                     // 192x8192 f32

  hipLaunchKernelGGL(norm_cast_kernel, dim3(2048), dim3(256), 0, stream,
                     zi, zj, zb, pos_p, out);
  hipLaunchKernelGGL(simloss_kernel, dim3(512), dim3(256), 0, stream,
                     zb, labels, pos_p, neg_p);
  hipLaunchKernelGGL(loss_kernel, dim3(128), dim3(256), 0, stream,
                     pos_p, neg_p, out);
}